// Round 3
// baseline (63.383 us; speedup 1.0000x reference)
//
#include <hip/hip_runtime.h>

typedef __attribute__((ext_vector_type(8))) short short8;
typedef __attribute__((ext_vector_type(16))) float f32x16;
typedef __attribute__((ext_vector_type(2))) float f32x2;
typedef __attribute__((ext_vector_type(4))) float f32x4;
typedef __attribute__((ext_vector_type(2))) unsigned int uint2v;

#define HW 1026
#define CH_STRIDE (HW * HW)          /* 1052676 */
#define TH 16                        /* output rows per tile     */
#define TW 32                        /* output cols per tile     */
#define LDS_ROWS 18                  /* TH + 2 halo              */
#define ROW_BYTES 1120               /* 34px*32B = 1088, +32 pad: row bank-phase 24 */
#define TILE_BYTES (LDS_ROWS * ROW_BYTES)   /* 20160 */
#define UNITS_PER_C4 (LDS_ROWS * 17) /* 306 units of 4ch x 2px  */
#define NUNITS (4 * UNITS_PER_C4)    /* 1224 */

__device__ __forceinline__ unsigned short f2bf(float f) {
    unsigned int u = __builtin_bit_cast(unsigned int, f);
    u += 0x7fffu + ((u >> 16) & 1u);
    return (unsigned short)(u >> 16);
}

// ---- issue global loads for one tile: 4ch x 2px units, f32x2 (8B-aligned) ----
__device__ __forceinline__ void stage_issue(const float* __restrict__ x, int h0, int w0,
                                            int tid, f32x2 (&vals)[5][4]) {
    #pragma unroll
    for (int k = 0; k < 5; ++k) {
        const int idx = tid + k * 256;
        if (idx < NUNITS) {
            const int c4  = idx / UNITS_PER_C4;
            const int rem = idx - c4 * UNITS_PER_C4;
            const int row = rem / 17;
            const int u   = rem - row * 17;
            const float* base = x + (4 * c4) * CH_STRIDE + (h0 + row) * HW + (w0 + 2 * u);
            #pragma unroll
            for (int j = 0; j < 4; ++j)
                vals[k][j] = *(const f32x2*)(base + j * CH_STRIDE);
        }
    }
}

// ---- convert + transpose into LDS buffer: [row][px][16ch] bf16, XOR-swizzled ----
__device__ __forceinline__ void stage_write(unsigned char* buf, int tid,
                                            const f32x2 (&vals)[5][4]) {
    #pragma unroll
    for (int k = 0; k < 5; ++k) {
        const int idx = tid + k * 256;
        if (idx < NUNITS) {
            const int c4  = idx / UNITS_PER_C4;
            const int rem = idx - c4 * UNITS_PER_C4;
            const int row = rem / 17;
            const int u   = rem - row * 17;
            #pragma unroll
            for (int p = 0; p < 2; ++p) {
                const int pp = 2 * u + p;
                const unsigned int lo  = (unsigned int)f2bf(vals[k][0][p]) |
                                         ((unsigned int)f2bf(vals[k][1][p]) << 16);
                const unsigned int hi2 = (unsigned int)f2bf(vals[k][2][p]) |
                                         ((unsigned int)f2bf(vals[k][3][p]) << 16);
                const int s16 = ((c4 >> 1) ^ (pp >> 2) ^ (pp >> 3)) & 1;
                const int off = row * ROW_BYTES + pp * 32 + s16 * 16 + (c4 & 1) * 8;
                uint2v t; t.x = lo; t.y = hi2;
                *(uint2v*)(buf + off) = t;
            }
        }
    }
}

// ---- 36 MFMAs + nt-stores for one tile ----
__device__ __forceinline__ void compute_store(const unsigned char* buf,
                                              const short8 (&af)[3][3],
                                              float* __restrict__ out,
                                              int h0, int w0, int wv, int n, int hi) {
    #pragma unroll
    for (int t = 0; t < 4; ++t) {
        const int baserow = wv * 4 + t;
        f32x16 acc;
        #pragma unroll
        for (int q = 0; q < 16; ++q) acc[q] = 0.0f;
        #pragma unroll
        for (int r = 0; r < 3; ++r) {
            #pragma unroll
            for (int s = 0; s < 3; ++s) {
                const int w   = n + s;
                const int s16 = (hi ^ (w >> 2) ^ (w >> 3)) & 1;
                const int off = (baserow + r) * ROW_BYTES + w * 32 + s16 * 16;
                const short8 bfr = *(const short8*)(buf + off);   // ds_read_b128
                acc = __builtin_amdgcn_mfma_f32_32x32x16_bf16(af[r][s], bfr, acc, 0, 0, 0);
            }
        }
        const int h = h0 + baserow;
        #pragma unroll
        for (int q = 0; q < 16; ++q) {
            const int o = (q & 3) + 8 * (q >> 2) + 4 * hi;
            __builtin_nontemporal_store(acc[q], out + (o << 20) + (h << 10) + (w0 + n));
        }
    }
}

__global__ __launch_bounds__(256, 4)
void gck3x3_mfma_kernel(const float* __restrict__ x,
                        const float* __restrict__ kern,
                        float* __restrict__ out) {
    __shared__ __attribute__((aligned(16))) unsigned char s_x[2][TILE_BYTES];

    const int tid  = threadIdx.x;
    const int lane = tid & 63;
    const int wv   = tid >> 6;
    const int n    = lane & 31;
    const int hi   = lane >> 5;

    // XCD-aware bijective swizzle over 1024 tile-pairs (1024 % 8 == 0)
    const int bid = blockIdx.x;
    const int swz = (bid & 7) * 128 + (bid >> 3);
    const int ph  = swz >> 5;            // 0..31: vertical pair index
    const int pw  = swz & 31;            // 0..31
    const int w0  = pw * TW;
    const int h0a = ph * 32;             // tile 0 rows
    const int h0b = h0a + TH;            // tile 1 rows

    f32x2 vals[5][4];

    // tile-0 x loads first (HBM critical path) ...
    stage_issue(x, h0a, w0, tid, vals);

    // ... then A fragments: 18 contiguous dwordx4 per lane from L2-resident kern
    short8 af[3][3];
    {
        float chunk[72];
        const float* kbase = kern + n * 144 + hi * 72;   // 72 contiguous floats
        #pragma unroll
        for (int j4 = 0; j4 < 18; ++j4)
            *(f32x4*)(chunk + 4 * j4) = *(const f32x4*)(kbase + 4 * j4);
        #pragma unroll
        for (int r = 0; r < 3; ++r)
            #pragma unroll
            for (int s = 0; s < 3; ++s) {
                short8 v;
                #pragma unroll
                for (int j = 0; j < 8; ++j)
                    v[j] = (short)f2bf(chunk[j * 9 + r * 3 + s]);
                af[r][s] = v;
            }
    }

    stage_write(&s_x[0][0], tid, vals);      // waits on tile-0 loads
    __syncthreads();

    stage_issue(x, h0b, w0, tid, vals);      // issue tile-1 loads EARLY
    __builtin_amdgcn_sched_barrier(0);       // pin: loads stay above compute

    compute_store(&s_x[0][0], af, out, h0a, w0, wv, n, hi);   // hides tile-1 fetch

    stage_write(&s_x[1][0], tid, vals);      // different buffer: no barrier needed before
    __syncthreads();

    compute_store(&s_x[1][0], af, out, h0b, w0, wv, n, hi);
}

extern "C" void kernel_launch(void* const* d_in, const int* in_sizes, int n_in,
                              void* d_out, int out_size, void* d_ws, size_t ws_size,
                              hipStream_t stream) {
    (void)in_sizes; (void)n_in; (void)d_ws; (void)ws_size; (void)out_size;
    const float* x    = (const float*)d_in[0];
    const float* kern = (const float*)d_in[1];
    float*       out  = (float*)d_out;
    gck3x3_mfma_kernel<<<1024, 256, 0, stream>>>(x, kern, out);
}